// Round 1
// baseline (934.242 us; speedup 1.0000x reference)
//
#include <hip/hip_runtime.h>
#include <math.h>

#define Bsz  1024
#define Tlen 128
#define Hdim 512
#define NCLS 10
#define NDIG 3
#define G4   2048   // 4*H

typedef short s8v __attribute__((ext_vector_type(8)));    // 8 bf16 (4 VGPRs)
typedef float f16v __attribute__((ext_vector_type(16)));  // 32x32 mfma acc

// ---- workspace layout (bytes) ----
// W6 : 2 MB  bf16 frag chunks: uint4 idx = (wn*32+ks)*64 + lane (unchanged)
// gxd: 24 KB fp32 [d][jp*4+g] (padded to 32 KB)
// LL : 2 x 2 MB tagged-granule h exchange (RCCL-LL style).
//      granule = 8B: low 4B = 2 bf16 of h, high 4B = step tag.
//      per chain (mt): 8192 granules; granule G maps to LDS uint index G of
//      the frag layout (uint4 q = G>>2 holds 8 bf16, pair p = G&3).
//      buffer parity: h_t lives in buffer t&1 with tag == t.
#define W6_OFF  0
#define GXD_OFF (2*1024*1024)
#define LL_OFF  (GXD_OFF + 32*1024)
#define LLBUF   262144ull   // ull granules per buffer (32 chains x 8192)

static __device__ __forceinline__ unsigned short f2bf(float f) {
    unsigned int u = __float_as_uint(f);
    u = (u + 0x7FFFu + ((u >> 16) & 1u)) >> 16;   // RNE
    return (unsigned short)u;
}
static __device__ __forceinline__ float bf2f(unsigned short s) {
    return __uint_as_float(((unsigned int)s) << 16);
}
static __device__ __forceinline__ s8v u2s(uint4 v) {
    union { uint4 u; s8v s; } x; x.u = v; return x.s;
}

// ---- prep: W6 frag chunks (unchanged layout) ----
__global__ __launch_bounds__(256) void prep_w6(const float* __restrict__ Wh,
                                               unsigned short* __restrict__ W6) {
    int idx = blockIdx.x * 256 + threadIdx.x;   // 0..131071
    int l  = idx & 63;
    int c  = idx >> 6;          // wn*32 + ks
    int ks = c & 31, wn = c >> 5;
    int n  = wn * 32 + (l & 31);
    int jp = n >> 2, g = n & 3;
    int row = g * Hdim + jp;
    int kb  = ks * 16 + (l >> 5) * 8;
    const float* src = &Wh[(size_t)row * Hdim + kb];
    unsigned int p0 = f2bf(src[0]) | ((unsigned int)f2bf(src[1]) << 16);
    unsigned int p1 = f2bf(src[2]) | ((unsigned int)f2bf(src[3]) << 16);
    unsigned int p2 = f2bf(src[4]) | ((unsigned int)f2bf(src[5]) << 16);
    unsigned int p3 = f2bf(src[6]) | ((unsigned int)f2bf(src[7]) << 16);
    ((uint4*)W6)[idx] = make_uint4(p0, p1, p2, p3);
}

__global__ __launch_bounds__(256) void prep_gxd(const float* __restrict__ emb,
                                                const float* __restrict__ Wx,
                                                const float* __restrict__ b,
                                                float* __restrict__ gxd) {
    int idx = blockIdx.x * 256 + threadIdx.x;
    if (idx >= NDIG * G4) return;
    int col = idx % G4;
    int d   = idx / G4;
    int jp  = col >> 2;
    int g   = col & 3;
    int row = g * Hdim + jp;
    gxd[idx] = emb[d * 2 + 0] * Wx[row * 2 + 0]
             + emb[d * 2 + 1] * Wx[row * 2 + 1]
             + b[row];
}

__global__ __launch_bounds__(256) void zero_state(float4* __restrict__ p, int n4) {
    int i = blockIdx.x * 256 + threadIdx.x;
    if (i < n4) p[i] = make_float4(0.f, 0.f, 0.f, 0.f);
}

// ---- stage one producer slice: poll tagged granules, unpack to LDS ----
// lr: granule base for this wave's slice (+i*64 per round-robin chunk)
// hl: LDS uint base (+i*64), writes low-4B of each fresh granule
static __device__ __forceinline__ void stage_slice(
    const unsigned long long* lr, unsigned int* hl, unsigned int want)
{
    unsigned long long g[16];
    unsigned int pend = 0xffffu;
    while (pend) {
#pragma unroll
        for (int i = 0; i < 16; i++)
            if (pend & (1u << i))
                g[i] = __hip_atomic_load(lr + i * 64, __ATOMIC_RELAXED,
                                         __HIP_MEMORY_SCOPE_AGENT);
#pragma unroll
        for (int i = 0; i < 16; i++)
            if ((pend & (1u << i)) && (unsigned int)(g[i] >> 32) == want)
                pend &= ~(1u << i);
    }
#pragma unroll
    for (int i = 0; i < 16; i++) hl[i * 64] = (unsigned int)g[i];
}

// ---- persistent LSTM: LL tagged-granule exchange, 1 barrier/step ----
// 256 blocks x 512 thr. mt = blk&31 (chain: 32 batch rows), nt = blk>>5
// (256 gate-cols). Producer stores h as self-tagged 8B granules (no drain,
// no flags); consumer wave w polls producer-nt=w's granules directly and
// unpacks into double-buffered LDS.
__global__ __launch_bounds__(512, 2) void lstm_persist(
    const uint4* __restrict__ W6, const float* __restrict__ gxd,
    const int* __restrict__ x, unsigned long long* __restrict__ ll,
    const float* __restrict__ Wp, const float* __restrict__ bp,
    float* __restrict__ out)
{
    __shared__ uint4 h_lds[2][2048];    // 64 KB  double-buffered h B-frags
    __shared__ float gxd_s[NDIG * G4];  // 24 KB
    __shared__ int   x_s[4096];         // 16 KB  [t][b_local]

    const int tid  = threadIdx.x;
    const int w    = tid >> 6;          // wave 0..7
    const int lane = tid & 63;
    const int hi   = lane >> 5;
    const int bl   = lane & 31;         // batch row (C col)
    const int mt   = blockIdx.x & 31;
    const int nt   = blockIdx.x >> 5;

    // A-resident W fragments: wave n-window = nt*256 + w*32 (32 gate-cols)
    s8v wfrag[32];
    {
        const uint4* wq = W6 + (size_t)((nt * 8 + w) * 32) * 64 + lane;
#pragma unroll
        for (int ks = 0; ks < 32; ks++) wfrag[ks] = u2s(wq[ks * 64]);
    }
    for (int i = tid; i < 4096; i += 512) {
        int b2 = i & 31, tt = i >> 5;
        x_s[tt * 32 + b2] = x[(mt * 32 + b2) * Tlen + tt];
    }
    for (int i = tid; i < NDIG * G4; i += 512) gxd_s[i] = gxd[i];
    __syncthreads();   // one-time init

    float c0 = 0.f, c1 = 0.f, c2 = 0.f, c3 = 0.f;
    const int jbase = nt * 64 + w * 8 + hi;           // jp for u: jbase + 2u
    // producer granule position (constant per thread): uint4 q of the chain
    const int q = (nt * 4 + (w >> 1)) * 64 + (w & 1) * 32 + bl;
    unsigned long long* llst = ll + (size_t)mt * 8192 + q * 4 + hi * 2;
    const unsigned long long* llld = ll + (size_t)mt * 8192 + w * 1024 + lane;
    unsigned int* hlb = (unsigned int*)h_lds;

#pragma unroll 1
    for (int t = 0; t < Tlen; t++) {
        const int par = t & 1;

        // ---- stage: wave w polls + unpacks producer-w's slice ----
        stage_slice(llld + (size_t)par * LLBUF,
                    hlb + par * 8192 + w * 1024 + lane, (unsigned int)t);
        __syncthreads();                   // all 8 slices in LDS buf[par]

        // ---- K loop: z^T tile (W = A from regs, h = B from LDS) ----
        f16v acc = {0,0,0,0,0,0,0,0,0,0,0,0,0,0,0,0};
        const uint4* hb = &h_lds[par][0];
#pragma unroll
        for (int ks = 0; ks < 32; ks++) {
            s8v hf = u2s(hb[ks * 64 + lane]);
            acc = __builtin_amdgcn_mfma_f32_32x32x16_bf16(wfrag[ks], hf, acc,
                                                          0, 0, 0);
        }

        // ---- in-register epilogue: lane = (b=bl, jp=jbase+2u, 4 gates) ----
        {
            int d = x_s[t * 32 + bl];
            float cc[4] = {c0, c1, c2, c3};
            unsigned short hh[4];
#pragma unroll
            for (int u = 0; u < 4; u++) {
                int jp = jbase + 2 * u;
                float4 g4 = *(const float4*)&gxd_s[d * G4 + jp * 4];
                float zg = acc[4*u+0] + g4.x;
                float zi = acc[4*u+1] + g4.y;
                float zf = acc[4*u+2] + g4.z;
                float zo = acc[4*u+3] + g4.w;
                float gv = 1.f - 2.f / (__expf(2.f * zg) + 1.f);
                float iv = 1.f / (1.f + __expf(-zi));
                float fv = 1.f / (1.f + __expf(-zf));
                float ov = 1.f / (1.f + __expf(-zo));
                float cn = gv * iv + cc[u] * fv;
                cc[u] = cn;
                hh[u] = f2bf((1.f - 2.f / (__expf(2.f * cn) + 1.f)) * ov);
            }
            c0 = cc[0]; c1 = cc[1]; c2 = cc[2]; c3 = cc[3];
            // repack even/odd jp across hi-halves -> 4 contiguous bf16
            unsigned int p01 = (unsigned int)hh[0] | ((unsigned int)hh[1] << 16);
            unsigned int p23 = (unsigned int)hh[2] | ((unsigned int)hh[3] << 16);
            unsigned int q01 = __shfl_xor(p01, 32);
            unsigned int q23 = __shfl_xor(p23, 32);
            unsigned int lo2, hi2;
            if (hi == 0) {
                lo2 = (p01 & 0xffffu) | ((q01 & 0xffffu) << 16);
                hi2 = (p01 >> 16) | (q01 & 0xffff0000u);
            } else {
                lo2 = (q23 & 0xffffu) | ((p23 & 0xffffu) << 16);
                hi2 = (q23 >> 16) | (p23 & 0xffff0000u);
            }
            // tagged-granule publish: data IS the flag. No drain, no flags.
            unsigned long long tg =
                ((unsigned long long)(unsigned int)(t + 1)) << 32;
            unsigned long long* lw = llst + (size_t)((t + 1) & 1) * LLBUF;
            __hip_atomic_store(lw,     (unsigned long long)lo2 | tg,
                               __ATOMIC_RELAXED, __HIP_MEMORY_SCOPE_AGENT);
            __hip_atomic_store(lw + 1, (unsigned long long)hi2 | tg,
                               __ATOMIC_RELAXED, __HIP_MEMORY_SCOPE_AGENT);
        }
    }

    // ---- head (nt==0 blocks): p = h.Wp + bp, log_softmax for 32 rows ----
    if (nt != 0) return;
    // final stage round: h_128 (tag 128, parity 0) into LDS buf0
    stage_slice(llld, hlb + w * 1024 + lane, (unsigned int)Tlen);
    __syncthreads();
    float* wp_s = gxd_s;   // 20 KB into 24 KB region (gxd no longer needed)
    for (int i = tid; i < Hdim * NCLS; i += 512) wp_s[i] = Wp[i];
    __syncthreads();

#pragma unroll
    for (int rr = 0; rr < 4; rr++) {
        int blr = w * 4 + rr;
        int b   = mt * 32 + blr;
        // frag layout: uint4 q=ks*64+l, elem j = h[l&31][ks*16+(l>>5)*8+j]
        // head lane wants k = lane*8+j  ->  q = (lane>>1)*64+(lane&1)*32+blr
        uint4 hq = h_lds[0][(lane >> 1) * 64 + (lane & 1) * 32 + blr];
        union { uint4 u; unsigned short s[8]; } hu; hu.u = hq;
        float a[NCLS];
#pragma unroll
        for (int c = 0; c < NCLS; c++) a[c] = 0.f;
#pragma unroll
        for (int j = 0; j < 8; j++) {
            int k = lane * 8 + j;
            float hvv = bf2f(hu.s[j]);
#pragma unroll
            for (int c = 0; c < NCLS; c++) a[c] += hvv * wp_s[k * NCLS + c];
        }
#pragma unroll
        for (int off = 32; off > 0; off >>= 1) {
#pragma unroll
            for (int c = 0; c < NCLS; c++) a[c] += __shfl_down(a[c], off);
        }
        if (lane == 0) {
            float p[NCLS], m = -1e30f;
#pragma unroll
            for (int c = 0; c < NCLS; c++) { p[c] = a[c] + bp[c]; m = fmaxf(m, p[c]); }
            float s = 0.f;
#pragma unroll
            for (int c = 0; c < NCLS; c++) s += __expf(p[c] - m);
            float lse = m + logf(s);
#pragma unroll
            for (int c = 0; c < NCLS; c++) out[b * NCLS + c] = p[c] - lse;
        }
    }
}

extern "C" void kernel_launch(void* const* d_in, const int* in_sizes, int n_in,
                              void* d_out, int out_size, void* d_ws, size_t ws_size,
                              hipStream_t stream) {
    const int*   x   = (const int*)d_in[0];
    const float* emb = (const float*)d_in[1];
    const float* Wx  = (const float*)d_in[2];
    const float* Wh  = (const float*)d_in[3];
    const float* b   = (const float*)d_in[4];
    const float* Wp  = (const float*)d_in[5];
    const float* bp  = (const float*)d_in[6];
    float* out = (float*)d_out;
    char*  ws  = (char*)d_ws;

    unsigned short*     W6  = (unsigned short*)(ws + W6_OFF);
    float*              gxd = (float*)(ws + GXD_OFF);
    unsigned long long* ll  = (unsigned long long*)(ws + LL_OFF);

    prep_w6<<<512, 256, 0, stream>>>(Wh, W6);
    prep_gxd<<<(NDIG * G4 + 255) / 256, 256, 0, stream>>>(emb, Wx, b, gxd);
    // zero both LL buffers (4 MB): tag 0 == h_0 available for step 0
    {
        int n4 = (4 * 1024 * 1024) / 16;
        zero_state<<<(n4 + 255) / 256, 256, 0, stream>>>((float4*)ll, n4);
    }

    void* args[] = { (void*)&W6, (void*)&gxd, (void*)&x, (void*)&ll,
                     (void*)&Wp, (void*)&bp, (void*)&out };
    hipLaunchCooperativeKernel((void*)lstm_persist, dim3(256), dim3(512),
                               args, 0, stream);
}

// Round 5
// 623.709 us; speedup vs baseline: 1.4979x; 1.4979x over previous
//
#include <hip/hip_runtime.h>
#include <math.h>

#define Bsz  1024
#define Tlen 128
#define Hdim 512
#define NCLS 10
#define NDIG 3
#define G4   2048   // 4*H

typedef short s8v __attribute__((ext_vector_type(8)));    // 8 bf16 (4 VGPRs)
typedef float f16v __attribute__((ext_vector_type(16)));  // 32x32 mfma acc

// ---- workspace layout (bytes) ----
// W6 : 2 MB  bf16 frag chunks (unchanged)
// gxd: 24 KB fp32 (padded to 32 KB)
// LL : 2 x 2 MB tagged-granule exchange, AGENT scope (guaranteed path)
// LLF: 2 x 2 MB tagged-granule exchange, plain-store/L2 (fast path, optional)
// granule = 8B: low 4B = 2 bf16 of h, high 4B = step tag. Producers ALWAYS
// dual-publish both buffers; consumers try fast (bounded) then slow.
#define W6_OFF  0
#define GXD_OFF (2*1024*1024)
#define LL_OFF  (GXD_OFF + 32*1024)
#define LLF_OFF (LL_OFF + 4*1024*1024)
#define LLBUF   262144ull   // ull granules per parity buffer (32 chains x 8192)
#define WS_FAST_NEED ((size_t)LLF_OFF + 4*1024*1024)

static __device__ __forceinline__ unsigned short f2bf(float f) {
    unsigned int u = __float_as_uint(f);
    u = (u + 0x7FFFu + ((u >> 16) & 1u)) >> 16;   // RNE
    return (unsigned short)u;
}
static __device__ __forceinline__ float bf2f(unsigned short s) {
    return __uint_as_float(((unsigned int)s) << 16);
}
static __device__ __forceinline__ s8v u2s(uint4 v) {
    union { uint4 u; s8v s; } x; x.u = v; return x.s;
}

// ---- prep: W6 frag chunks (unchanged layout) ----
__global__ __launch_bounds__(256) void prep_w6(const float* __restrict__ Wh,
                                               unsigned short* __restrict__ W6) {
    int idx = blockIdx.x * 256 + threadIdx.x;   // 0..131071
    int l  = idx & 63;
    int c  = idx >> 6;          // wn*32 + ks
    int ks = c & 31, wn = c >> 5;
    int n  = wn * 32 + (l & 31);
    int jp = n >> 2, g = n & 3;
    int row = g * Hdim + jp;
    int kb  = ks * 16 + (l >> 5) * 8;
    const float* src = &Wh[(size_t)row * Hdim + kb];
    unsigned int p0 = f2bf(src[0]) | ((unsigned int)f2bf(src[1]) << 16);
    unsigned int p1 = f2bf(src[2]) | ((unsigned int)f2bf(src[3]) << 16);
    unsigned int p2 = f2bf(src[4]) | ((unsigned int)f2bf(src[5]) << 16);
    unsigned int p3 = f2bf(src[6]) | ((unsigned int)f2bf(src[7]) << 16);
    ((uint4*)W6)[idx] = make_uint4(p0, p1, p2, p3);
}

__global__ __launch_bounds__(256) void prep_gxd(const float* __restrict__ emb,
                                                const float* __restrict__ Wx,
                                                const float* __restrict__ b,
                                                float* __restrict__ gxd) {
    int idx = blockIdx.x * 256 + threadIdx.x;
    if (idx >= NDIG * G4) return;
    int col = idx % G4;
    int d   = idx / G4;
    int jp  = col >> 2;
    int g   = col & 3;
    int row = g * Hdim + jp;
    gxd[idx] = emb[d * 2 + 0] * Wx[row * 2 + 0]
             + emb[d * 2 + 1] * Wx[row * 2 + 1]
             + b[row];
}

__global__ __launch_bounds__(256) void zero_state(float4* __restrict__ p, int n4) {
    int i = blockIdx.x * 256 + threadIdx.x;
    if (i < n4) p[i] = make_float4(0.f, 0.f, 0.f, 0.f);
}

// ---- SLOW stage (agent-scope tagged granules — round-1-proven; always
// terminates: producers publish unconditionally) ----
static __device__ __forceinline__ void stage_slow(
    const unsigned long long* lr, unsigned int* hl, unsigned int want)
{
    unsigned long long g[16];
    unsigned int pend = 0xffffu;
    int rr = 0;
    while (pend) {
#pragma unroll
        for (int i = 0; i < 16; i++)
            if (pend & (1u << i))
                g[i] = __hip_atomic_load(lr + i * 64, __ATOMIC_RELAXED,
                                         __HIP_MEMORY_SCOPE_AGENT);
#pragma unroll
        for (int i = 0; i < 16; i++)
            if ((pend & (1u << i)) && (unsigned int)(g[i] >> 32) == want)
                pend &= ~(1u << i);
        if (pend && ++rr > 2) __builtin_amdgcn_s_sleep(1);
    }
#pragma unroll
    for (int i = 0; i < 16; i++) hl[i * 64] = (unsigned int)g[i];
}

// ---- FAST try (bounded): sc0 loads (L1-bypass, L2-hit) of the plain-store
// copy. Single asm block: all loads + waitcnt together (no hoisting hazard),
// every output early-clobbered (async dest must not alias address regs).
// Re-loading already-valid granules is safe: a granule's parity slot cannot
// be rewritten until this consumer publishes its own next h (tag monotone,
// producer at most 1 step ahead). Returns 1 on success (LDS written).
static __device__ __forceinline__ int try_fast(
    const unsigned long long* lr, unsigned int* hl, unsigned int want,
    int rounds)
{
    const unsigned long long* lrb = lr + 512;   // +4096 B (13-bit imm limit)
    for (int r = 0; r < rounds; ++r) {
        unsigned long long g0,g1,g2,g3,g4,g5,g6,g7,g8,g9,g10,g11,g12,g13,g14,g15;
        asm volatile(
            "global_load_dwordx2 %[g0],  %[a], off sc0\n\t"
            "global_load_dwordx2 %[g1],  %[a], off offset:512 sc0\n\t"
            "global_load_dwordx2 %[g2],  %[a], off offset:1024 sc0\n\t"
            "global_load_dwordx2 %[g3],  %[a], off offset:1536 sc0\n\t"
            "global_load_dwordx2 %[g4],  %[a], off offset:2048 sc0\n\t"
            "global_load_dwordx2 %[g5],  %[a], off offset:2560 sc0\n\t"
            "global_load_dwordx2 %[g6],  %[a], off offset:3072 sc0\n\t"
            "global_load_dwordx2 %[g7],  %[a], off offset:3584 sc0\n\t"
            "global_load_dwordx2 %[g8],  %[b], off sc0\n\t"
            "global_load_dwordx2 %[g9],  %[b], off offset:512 sc0\n\t"
            "global_load_dwordx2 %[g10], %[b], off offset:1024 sc0\n\t"
            "global_load_dwordx2 %[g11], %[b], off offset:1536 sc0\n\t"
            "global_load_dwordx2 %[g12], %[b], off offset:2048 sc0\n\t"
            "global_load_dwordx2 %[g13], %[b], off offset:2560 sc0\n\t"
            "global_load_dwordx2 %[g14], %[b], off offset:3072 sc0\n\t"
            "global_load_dwordx2 %[g15], %[b], off offset:3584 sc0\n\t"
            "s_waitcnt vmcnt(0)"
            : [g0]"=&v"(g0),[g1]"=&v"(g1),[g2]"=&v"(g2),[g3]"=&v"(g3),
              [g4]"=&v"(g4),[g5]"=&v"(g5),[g6]"=&v"(g6),[g7]"=&v"(g7),
              [g8]"=&v"(g8),[g9]"=&v"(g9),[g10]"=&v"(g10),[g11]"=&v"(g11),
              [g12]"=&v"(g12),[g13]"=&v"(g13),[g14]"=&v"(g14),[g15]"=&v"(g15)
            : [a]"v"(lr), [b]"v"(lrb)
            : "memory");
        int ok = ((unsigned int)(g0  >> 32) == want) & ((unsigned int)(g1  >> 32) == want)
               & ((unsigned int)(g2  >> 32) == want) & ((unsigned int)(g3  >> 32) == want)
               & ((unsigned int)(g4  >> 32) == want) & ((unsigned int)(g5  >> 32) == want)
               & ((unsigned int)(g6  >> 32) == want) & ((unsigned int)(g7  >> 32) == want)
               & ((unsigned int)(g8  >> 32) == want) & ((unsigned int)(g9  >> 32) == want)
               & ((unsigned int)(g10 >> 32) == want) & ((unsigned int)(g11 >> 32) == want)
               & ((unsigned int)(g12 >> 32) == want) & ((unsigned int)(g13 >> 32) == want)
               & ((unsigned int)(g14 >> 32) == want) & ((unsigned int)(g15 >> 32) == want);
        if (__all(ok)) {
            hl[0*64]=(unsigned int)g0;   hl[1*64]=(unsigned int)g1;
            hl[2*64]=(unsigned int)g2;   hl[3*64]=(unsigned int)g3;
            hl[4*64]=(unsigned int)g4;   hl[5*64]=(unsigned int)g5;
            hl[6*64]=(unsigned int)g6;   hl[7*64]=(unsigned int)g7;
            hl[8*64]=(unsigned int)g8;   hl[9*64]=(unsigned int)g9;
            hl[10*64]=(unsigned int)g10; hl[11*64]=(unsigned int)g11;
            hl[12*64]=(unsigned int)g12; hl[13*64]=(unsigned int)g13;
            hl[14*64]=(unsigned int)g14; hl[15*64]=(unsigned int)g15;
            return 1;
        }
        __builtin_amdgcn_s_sleep(1);
    }
    return 0;
}

// ---- persistent LSTM: dual-publish + bounded-fast/guaranteed-slow stage ----
__global__ __launch_bounds__(512, 2) void lstm_persist(
    const uint4* __restrict__ W6, const float* __restrict__ gxd,
    const int* __restrict__ x, unsigned long long* __restrict__ ll,
    unsigned long long* __restrict__ llf, int fasten,
    const float* __restrict__ Wp, const float* __restrict__ bp,
    float* __restrict__ out)
{
    __shared__ uint4 h_lds[2][2048];    // 64 KB  double-buffered h B-frags
    __shared__ float gxd_s[NDIG * G4];  // 24 KB
    __shared__ int   x_s[4096];         // 16 KB  [t][b_local]

    const int tid  = threadIdx.x;
    const int w    = tid >> 6;          // wave 0..7
    const int lane = tid & 63;
    const int hi   = lane >> 5;
    const int bl   = lane & 31;         // batch row (C col)
    const int mt   = blockIdx.x & 31;
    const int nt   = blockIdx.x >> 5;

    // A-resident W fragments: wave n-window = nt*256 + w*32 (32 gate-cols)
    s8v wfrag[32];
    {
        const uint4* wq = W6 + (size_t)((nt * 8 + w) * 32) * 64 + lane;
#pragma unroll
        for (int ks = 0; ks < 32; ks++) wfrag[ks] = u2s(wq[ks * 64]);
    }
    for (int i = tid; i < 4096; i += 512) {
        int b2 = i & 31, tt = i >> 5;
        x_s[tt * 32 + b2] = x[(mt * 32 + b2) * Tlen + tt];
    }
    for (int i = tid; i < NDIG * G4; i += 512) gxd_s[i] = gxd[i];
    __syncthreads();   // one-time init

    float c0 = 0.f, c1 = 0.f, c2 = 0.f, c3 = 0.f;
    const int jbase = nt * 64 + w * 8 + hi;           // jp for u: jbase + 2u
    const int q = (nt * 4 + (w >> 1)) * 64 + (w & 1) * 32 + bl;
    unsigned long long*       llst  = ll  + (size_t)mt * 8192 + q * 4 + hi * 2;
    unsigned long long*       llstf = llf + (size_t)mt * 8192 + q * 4 + hi * 2;
    const unsigned long long* llld  = ll  + (size_t)mt * 8192 + w * 1024 + lane;
    const unsigned long long* llfld = llf + (size_t)mt * 8192 + w * 1024 + lane;
    unsigned int* hlb = (unsigned int*)h_lds;

    int tryFast = fasten;   // per-wave; wave-uniform by construction
    int streak  = 0;        // consecutive fast failures

#pragma unroll 1
    for (int t = 0; t < Tlen; t++) {
        const int par = t & 1;

        // ---- stage: wave w polls producer-w's slice (fast try, slow sure) ----
        {
            unsigned int* hlp = hlb + par * 8192 + w * 1024 + lane;
            int fs = 0;
            if (tryFast) {
                fs = try_fast(llfld + (size_t)par * LLBUF, hlp,
                              (unsigned int)t, 24);
                if (fs) streak = 0;
                else if (++streak >= 3) tryFast = 0;
            }
            if (!fs)
                stage_slow(llld + (size_t)par * LLBUF, hlp, (unsigned int)t);
        }
        __syncthreads();                   // all 8 slices in LDS buf[par]

        // ---- K loop: z^T tile (W = A from regs, h = B from LDS) ----
        f16v acc = {0,0,0,0,0,0,0,0,0,0,0,0,0,0,0,0};
        const uint4* hb = &h_lds[par][0];
#pragma unroll
        for (int ks = 0; ks < 32; ks++) {
            s8v hf = u2s(hb[ks * 64 + lane]);
            acc = __builtin_amdgcn_mfma_f32_32x32x16_bf16(wfrag[ks], hf, acc,
                                                          0, 0, 0);
        }

        // ---- in-register epilogue: lane = (b=bl, jp=jbase+2u, 4 gates) ----
        {
            int d = x_s[t * 32 + bl];
            float cc[4] = {c0, c1, c2, c3};
            unsigned short hh[4];
#pragma unroll
            for (int u = 0; u < 4; u++) {
                int jp = jbase + 2 * u;
                float4 g4 = *(const float4*)&gxd_s[d * G4 + jp * 4];
                float zg = acc[4*u+0] + g4.x;
                float zi = acc[4*u+1] + g4.y;
                float zf = acc[4*u+2] + g4.z;
                float zo = acc[4*u+3] + g4.w;
                float gv = 1.f - 2.f / (__expf(2.f * zg) + 1.f);
                float iv = 1.f / (1.f + __expf(-zi));
                float fv = 1.f / (1.f + __expf(-zf));
                float ov = 1.f / (1.f + __expf(-zo));
                float cn = gv * iv + cc[u] * fv;
                cc[u] = cn;
                hh[u] = f2bf((1.f - 2.f / (__expf(2.f * cn) + 1.f)) * ov);
            }
            c0 = cc[0]; c1 = cc[1]; c2 = cc[2]; c3 = cc[3];
            unsigned int p01 = (unsigned int)hh[0] | ((unsigned int)hh[1] << 16);
            unsigned int p23 = (unsigned int)hh[2] | ((unsigned int)hh[3] << 16);
            unsigned int q01 = __shfl_xor(p01, 32);
            unsigned int q23 = __shfl_xor(p23, 32);
            unsigned int lo2, hi2;
            if (hi == 0) {
                lo2 = (p01 & 0xffffu) | ((q01 & 0xffffu) << 16);
                hi2 = (p01 >> 16) | (q01 & 0xffff0000u);
            } else {
                lo2 = (q23 & 0xffffu) | ((p23 & 0xffffu) << 16);
                hi2 = (q23 >> 16) | (p23 & 0xffff0000u);
            }
            // tagged-granule dual publish: data IS the flag; no waits
            const unsigned long long tg =
                ((unsigned long long)(unsigned int)(t + 1)) << 32;
            const unsigned long long v0 = (unsigned long long)lo2 | tg;
            const unsigned long long v1 = (unsigned long long)hi2 | tg;
            const size_t pofs = (size_t)((t + 1) & 1) * LLBUF;
            if (fasten) {   // plain stores -> write-through L1 -> shared L2
                unsigned long long* fw = llstf + pofs;
                fw[0] = v0;
                fw[1] = v1;
            }
            unsigned long long* lw = llst + pofs;   // agent scope (guaranteed)
            __hip_atomic_store(lw,     v0, __ATOMIC_RELAXED,
                               __HIP_MEMORY_SCOPE_AGENT);
            __hip_atomic_store(lw + 1, v1, __ATOMIC_RELAXED,
                               __HIP_MEMORY_SCOPE_AGENT);
        }
    }

    // ---- head (nt==0 blocks): p = h.Wp + bp, log_softmax for 32 rows ----
    if (nt != 0) return;
    {
        unsigned int* hlp = hlb + w * 1024 + lane;   // h_128: parity 0, tag 128
        int fs = tryFast ? try_fast(llfld, hlp, (unsigned int)Tlen, 64) : 0;
        if (!fs) stage_slow(llld, hlp, (unsigned int)Tlen);
    }
    __syncthreads();
    float* wp_s = gxd_s;   // 20 KB into 24 KB region (gxd no longer needed)
    for (int i = tid; i < Hdim * NCLS; i += 512) wp_s[i] = Wp[i];
    __syncthreads();

#pragma unroll
    for (int rr = 0; rr < 4; rr++) {
        int blr = w * 4 + rr;
        int b   = mt * 32 + blr;
        uint4 hq = h_lds[0][(lane >> 1) * 64 + (lane & 1) * 32 + blr];
        union { uint4 u; unsigned short s[8]; } hu; hu.u = hq;
        float a[NCLS];
#pragma unroll
        for (int c = 0; c < NCLS; c++) a[c] = 0.f;
#pragma unroll
        for (int j = 0; j < 8; j++) {
            int k = lane * 8 + j;
            float hvv = bf2f(hu.s[j]);
#pragma unroll
            for (int c = 0; c < NCLS; c++) a[c] += hvv * wp_s[k * NCLS + c];
        }
#pragma unroll
        for (int off = 32; off > 0; off >>= 1) {
#pragma unroll
            for (int c = 0; c < NCLS; c++) a[c] += __shfl_down(a[c], off);
        }
        if (lane == 0) {
            float p[NCLS], m = -1e30f;
#pragma unroll
            for (int c = 0; c < NCLS; c++) { p[c] = a[c] + bp[c]; m = fmaxf(m, p[c]); }
            float s = 0.f;
#pragma unroll
            for (int c = 0; c < NCLS; c++) s += __expf(p[c] - m);
            float lse = m + logf(s);
#pragma unroll
            for (int c = 0; c < NCLS; c++) out[b * NCLS + c] = p[c] - lse;
        }
    }
}

extern "C" void kernel_launch(void* const* d_in, const int* in_sizes, int n_in,
                              void* d_out, int out_size, void* d_ws, size_t ws_size,
                              hipStream_t stream) {
    const int*   x   = (const int*)d_in[0];
    const float* emb = (const float*)d_in[1];
    const float* Wx  = (const float*)d_in[2];
    const float* Wh  = (const float*)d_in[3];
    const float* b   = (const float*)d_in[4];
    const float* Wp  = (const float*)d_in[5];
    const float* bp  = (const float*)d_in[6];
    float* out = (float*)d_out;
    char*  ws  = (char*)d_ws;

    int fasten = (ws_size >= WS_FAST_NEED) ? 1 : 0;

    unsigned short*     W6  = (unsigned short*)(ws + W6_OFF);
    float*              gxd = (float*)(ws + GXD_OFF);
    unsigned long long* ll  = (unsigned long long*)(ws + LL_OFF);
    unsigned long long* llf = (unsigned long long*)(ws + (fasten ? LLF_OFF
                                                                 : LL_OFF));

    prep_w6<<<512, 256, 0, stream>>>(Wh, W6);
    prep_gxd<<<(NDIG * G4 + 255) / 256, 256, 0, stream>>>(emb, Wx, b, gxd);
    // zero LL (+LLF when enabled): tag 0 == h_0 available for step 0
    {
        int nbytes = (fasten ? 8 : 4) * 1024 * 1024;
        int n4 = nbytes / 16;
        zero_state<<<(n4 + 255) / 256, 256, 0, stream>>>(
            (float4*)(ws + LL_OFF), n4);
    }

    void* args[] = { (void*)&W6, (void*)&gxd, (void*)&x, (void*)&ll,
                     (void*)&llf, (void*)&fasten,
                     (void*)&Wp, (void*)&bp, (void*)&out };
    hipLaunchCooperativeKernel((void*)lstm_persist, dim3(256), dim3(512),
                               args, 0, stream);
}